// Round 1
// 818.902 us; speedup vs baseline: 1.0001x; 1.0001x over previous
//
#include <hip/hip_runtime.h>
#include <hip/hip_bf16.h>
#include <string.h>

#define NN 100000
#define TT 64
#define EE 1000000
#define LOG2E 1.44269504088896340736f

typedef __attribute__((ext_vector_type(8))) short bf16x8;
typedef __attribute__((ext_vector_type(4))) float f32x4;
typedef unsigned int u32;
typedef unsigned short u16;

__device__ __forceinline__ float bflo(u32 u) { return __builtin_bit_cast(float, u << 16); }
__device__ __forceinline__ float bfhi(u32 u) { return __builtin_bit_cast(float, u & 0xffff0000u); }
__device__ __forceinline__ u16 f2bf(float f) {
    u32 u = __builtin_bit_cast(u32, f);
    return (u16)((u + 0x7fffu + ((u >> 16) & 1u)) >> 16);
}
__device__ __forceinline__ u32 pack2(float a, float b) {
    return (u32)f2bf(a) | ((u32)f2bf(b) << 16);
}
// v_cvt_pk_bf16_f32 path (gfx950); memcpy avoids non-trivially-copyable bit_cast
__device__ __forceinline__ u32 pack2c(float a, float b) {
    __hip_bfloat162 t = __float22bfloat162_rn(make_float2(a, b));
    u32 r;
    __builtin_memcpy(&r, &t, 4);
    return r;
}
// raw v_exp_f32 — avoids OCML's guarded __ocml_exp2_f32 (harness compiles w/o -ffast-math)
__device__ __forceinline__ float ex2(float x) { return __builtin_amdgcn_exp2f(x); }
__device__ __forceinline__ float fast_rcp(float x) { return __builtin_amdgcn_rcpf(x); }
__device__ __forceinline__ float tanhf_fast(float v) {
    return fmaf(2.f, fast_rcp(1.f + ex2(-2.f * LOG2E * v)), -1.f);
}
#define MFMA16(A, B, C) __builtin_amdgcn_mfma_f32_16x16x32_bf16((A), (B), (C), 0, 0, 0)

// ---------------------------------------------------------------------------
// LSTM round-13 restructure ("gate-split"):
//   Block = 64 nodes, 4 waves. Wave w owns 64 gate rows (units 16w..16w+15 for
//   each of i,f,g,o) for ALL 64 nodes. A-fragments (w_hh, pre-scaled) live in
//   32 VGPRs/wave; tail (w_ih,bias) fragments in 8 VGPRs.  h is block-shared,
//   double-buffered in LDS ([64][72] bf16 x2) with one barrier per timestep.
//   Per-step LDS ops: 12 reads + 4 writes (was 51 in the wfrag design).
//   LDS: 21 KB (was 47 KB) -> residency becomes VGPR-capped (4 waves/SIMD).
//
// LAUNCH-BOUNDS LAWS (confirmed rounds 4-12 on this toolchain):
//   * VGPR cap = 256/min_waves.  84 regs (min=3) SPILLS a body this size;
//     128 regs (min=2) fits.  Keep amdgpu_waves_per_eu(2,4):
//     128-reg budget + residency may rise to 4 waves/EU.
//   * launch_bounds 2nd arg pins occupancy [a,a]; don't use it.
// ---------------------------------------------------------------------------
__global__ __launch_bounds__(256)
__attribute__((amdgpu_waves_per_eu(2, 4))) void lstm_kernel(
    const float* __restrict__ x,     // [NN*TT*2]
    const float* __restrict__ w_ih,  // [256*2]
    const float* __restrict__ w_hh,  // [256*64]
    const float* __restrict__ b_ih,  // [256]
    const float* __restrict__ b_hh,  // [256]
    u16* __restrict__ h_out)         // [NN*64] bf16 (internal format)
{
    __shared__ __align__(16) u16 h_sh[2][64 * 72];   // 18,432 B  double-buffered h
    __shared__ __align__(8) u32 x_lds[64 * 10];      //  2,560 B  packed bf16 x chunk

    const int tid = threadIdx.x;
    const int wv = tid >> 6, lane = tid & 63;
    const int q = lane >> 4, cl = lane & 15;

    // ---- stage A = w_hh fragments for this wave's 64 gate rows, in registers.
    // Fragment (G, kh): lane (q,cl) holds A[row=cl][k = kh*32 + q*8 .. +7],
    // row-global = G*64 + 16*wv + cl, pre-scaled (g-gate: 2*LOG2E, else LOG2E).
    bf16x8 aI0, aI1, aF0, aF1, aG0, aG1, aO0, aO1;
    uint2 wtI, wtF, wtG, wtO;
    {
        const int rbase = wv * 16 + cl;
#define LOAD_A(D0, D1, G, SC)                                                \
        {                                                                    \
            const float* wr_ = w_hh + ((G) * 64 + rbase) * 64 + q * 8;       \
            float4 u0 = *(const float4*)(wr_);                               \
            float4 u1 = *(const float4*)(wr_ + 4);                           \
            uint4 t;                                                         \
            t.x = pack2(u0.x * (SC), u0.y * (SC));                           \
            t.y = pack2(u0.z * (SC), u0.w * (SC));                           \
            t.z = pack2(u1.x * (SC), u1.y * (SC));                           \
            t.w = pack2(u1.z * (SC), u1.w * (SC));                           \
            D0 = __builtin_bit_cast(bf16x8, t);                              \
            float4 v0 = *(const float4*)(wr_ + 32);                          \
            float4 v1 = *(const float4*)(wr_ + 36);                          \
            t.x = pack2(v0.x * (SC), v0.y * (SC));                           \
            t.y = pack2(v0.z * (SC), v0.w * (SC));                           \
            t.z = pack2(v1.x * (SC), v1.y * (SC));                           \
            t.w = pack2(v1.z * (SC), v1.w * (SC));                           \
            D1 = __builtin_bit_cast(bf16x8, t);                              \
        }
        LOAD_A(aI0, aI1, 0, LOG2E)
        LOAD_A(aF0, aF1, 1, LOG2E)
        LOAD_A(aG0, aG1, 2, 2.f * LOG2E)
        LOAD_A(aO0, aO1, 3, LOG2E)
#undef LOAD_A
        // tail A rows: (wih0*sc, wih1*sc, bias*sc, 0...) -- only q==0 lanes
        // hold k=0..7, others must be zero.
#define LOAD_WT(D, G, SC)                                                    \
        if (q == 0) {                                                        \
            int row = (G) * 64 + rbase;                                      \
            D = make_uint2(                                                  \
                pack2(w_ih[row * 2 + 0] * (SC), w_ih[row * 2 + 1] * (SC)),   \
                (u32)f2bf((b_ih[row] + b_hh[row]) * (SC)));                  \
        } else D = make_uint2(0u, 0u);
        LOAD_WT(wtI, 0, LOG2E)
        LOAD_WT(wtF, 1, LOG2E)
        LOAD_WT(wtG, 2, 2.f * LOG2E)
        LOAD_WT(wtO, 3, LOG2E)
#undef LOAD_WT
    }

    // zero h buffer 0 (step 0 reads it)
    {
        u32* z = (u32*)h_sh[0];
        for (int i = tid; i < 2304; i += 256) z[i] = 0u;
    }

    // x chunk plan: chunk = 8 steps; block-wide 256 float4 = 1/thread covers
    // 64 nodes x 8 steps x 2 comps.  thread -> (node = tid>>2, f4 = tid&3).
    const int nodeL = tid >> 2, f4 = tid & 3;
    int gnd = blockIdx.x * 64 + nodeL;
    gnd = gnd < NN ? gnd : NN - 1;
    const float* px = x + ((size_t)gnd * 64 + f4 * 2) * 2;
    float4 xr = *(const float4*)px;   // chunk 0 in flight

    float cst[16];
#pragma unroll
    for (int i = 0; i < 16; ++i) cst[i] = 0.f;

    const f32x4 zero4 = {0.f, 0.f, 0.f, 0.f};
    const int rd16 = cl * 72 + q * 8;            // B-frag u16 offset (+ct*1152)
    const int wr16 = cl * 72 + wv * 16 + q * 4;  // h-write u16 offset (+ct*1152)
    const int x16 = cl * 10;                     // x u16.. (u32) offset (+ct*160)

    // one timestep: read h from HR, write new h to HW, x slot SL (0..7)
    auto step = [&](const u16* hr_, u16* hw_, int SL) {
#pragma unroll
        for (int ct = 0; ct < 4; ++ct) {
            bf16x8 bh0 = *(const bf16x8*)(hr_ + ct * 1152 + rd16);
            bf16x8 bh1 = *(const bf16x8*)(hr_ + ct * 1152 + rd16 + 32);
            uint4 xt;
            xt.x = x_lds[ct * 160 + x16 + SL];
            xt.y = 0x00003F80u;   // bf16(1.0) in slot k=2 (bias multiplier)
            xt.z = 0u; xt.w = 0u;
            bf16x8 bx = __builtin_bit_cast(bf16x8, xt);
            f32x4 accI, accF, accG, accO;
            uint4 wxu; wxu.z = 0u; wxu.w = 0u;
            wxu.x = wtI.x; wxu.y = wtI.y;
            accI = MFMA16(aI0, bh0, zero4);
            accI = MFMA16(aI1, bh1, accI);
            accI = MFMA16(__builtin_bit_cast(bf16x8, wxu), bx, accI);
            wxu.x = wtF.x; wxu.y = wtF.y;
            accF = MFMA16(aF0, bh0, zero4);
            accF = MFMA16(aF1, bh1, accF);
            accF = MFMA16(__builtin_bit_cast(bf16x8, wxu), bx, accF);
            wxu.x = wtG.x; wxu.y = wtG.y;
            accG = MFMA16(aG0, bh0, zero4);
            accG = MFMA16(aG1, bh1, accG);
            accG = MFMA16(__builtin_bit_cast(bf16x8, wxu), bx, accG);
            wxu.x = wtO.x; wxu.y = wtO.y;
            accO = MFMA16(aO0, bh0, zero4);
            accO = MFMA16(aO1, bh1, accO);
            accO = MFMA16(__builtin_bit_cast(bf16x8, wxu), bx, accO);
            // elementwise: node = 16ct+cl, unit u = 16*wv + 4q + r
            float h0, h1, h2, h3;
#define ACT(R, HOUT)                                                     \
            {                                                            \
                float ig = fast_rcp(1.f + ex2(-accI[R]));                \
                float fg = fast_rcp(1.f + ex2(-accF[R]));                \
                float gg = fmaf(2.f, fast_rcp(1.f + ex2(-accG[R])), -1.f); \
                float og = fast_rcp(1.f + ex2(-accO[R]));                \
                float cc = fmaf(fg, cst[ct * 4 + R], ig * gg);           \
                cst[ct * 4 + R] = cc;                                    \
                HOUT = og * tanhf_fast(cc);                              \
            }
            ACT(0, h0) ACT(1, h1) ACT(2, h2) ACT(3, h3)
#undef ACT
            *((uint2*)(hw_ + ct * 1152 + wr16)) =
                make_uint2(pack2c(h0, h1), pack2c(h2, h3));
        }
    };

    for (int c = 0; c < 8; ++c) {
        // commit chunk c (prev steps all barriered -> WAR on x_lds safe)
        *((uint2*)(x_lds + nodeL * 10 + f4 * 2)) =
            make_uint2(pack2c(xr.x, xr.y), pack2c(xr.z, xr.w));
        if (c < 7) xr = *(const float4*)(px + (c + 1) * 16);
        __syncthreads();  // x_lds (and chunk-0: zeroed h) visible
        for (int s2 = 0; s2 < 4; ++s2) {
            step(h_sh[0], h_sh[1], s2 * 2);
            __syncthreads();
            step(h_sh[1], h_sh[0], s2 * 2 + 1);
            __syncthreads();
        }
    }
    // 64 steps done, final h in h_sh[0]; write coalesced u32 pairs
#pragma unroll
    for (int i = 0; i < 8; ++i) {
        int id = i * 256 + tid;
        int row = id >> 5, col2 = (id & 31) * 2;
        int nd = blockIdx.x * 64 + row;
        if (nd < NN) {
            u32 u = *(const u32*)(h_sh[0] + row * 72 + col2);
            *((u32*)(h_out + (size_t)nd * 64 + col2)) = u;
        }
    }
}

// ---------------------------------------------------------------------------
// watt[v][k] = sum_d att_v[d] * gat_w[head_v*64+d][k]   (v: 0=src h0, 1=src h1,
// 2=dst h0, 3=dst h1).  Folds attention dots into the xh GEMM as extra rows.
// ---------------------------------------------------------------------------
__global__ void watt_kernel(const float* __restrict__ gat_w,
                            const float* __restrict__ att_src,
                            const float* __restrict__ att_dst,
                            float* __restrict__ watt) {  // [4*64]
    int tid = threadIdx.x;
    int v = tid >> 6, k = tid & 63;
    int head = v & 1;
    const float* att = (v < 2) ? att_src : att_dst;
    float acc = 0.f;
#pragma unroll 8
    for (int d = 0; d < 64; ++d)
        acc = fmaf(att[head * 64 + d], gat_w[(head * 64 + d) * 64 + k], acc);
    watt[v * 64 + k] = acc;
}

// ---------------------------------------------------------------------------
// xh via MFMA: one wave per 16 nodes. A = gat_w tiles (LDS), B = h (global).
// D[col = t*16+q*4+r][node = cl]; tiles t/t+4 = head0/head1 at same lane.
// watt tile: q==0 lanes hold (asrc0, asrc1, adst0, adst1) for node cl.
// ---------------------------------------------------------------------------
__global__ __launch_bounds__(256, 2) void xh_kernel(
    const u16* __restrict__ h,        // [NN*64] bf16 (internal)
    const float* __restrict__ gat_w,  // [128*64] f32
    const float* __restrict__ watt,   // [4*64] f32
    u32* __restrict__ xh,             // [NN*64] packed bf16 pairs
    float2* __restrict__ asrc,
    float2* __restrict__ adst)
{
    __shared__ __align__(16) u16 afrag[16 * 64 * 8];   // 16 KB
    const int tid = threadIdx.x;
    const int wv = tid >> 6, lane = tid & 63;
    const int q = lane >> 4, cl = lane & 15;

    // stage A = gat_w fragments (tile t: rows t*16..+15 = output cols)
    for (int f = wv; f < 16; f += 4) {
        int t = f >> 1, kh = f & 1;
        const float4* s4 = (const float4*)(gat_w + (t * 16 + cl) * 64 + kh * 32 + q * 8);
        float4 u0 = s4[0], u1 = s4[1];
        u16* d = afrag + (f * 64 + lane) * 8;
        d[0] = f2bf(u0.x); d[1] = f2bf(u0.y); d[2] = f2bf(u0.z); d[3] = f2bf(u0.w);
        d[4] = f2bf(u1.x); d[5] = f2bf(u1.y); d[6] = f2bf(u1.z); d[7] = f2bf(u1.w);
    }
    // watt A-fragments in registers (rows cl<4 = att vectors, else 0)
    uint4 wa0u = make_uint4(0u, 0u, 0u, 0u), wa1u = wa0u;
    if (cl < 4) {
        const float* wp = watt + cl * 64;
        float4 a = *(const float4*)(wp + q * 8), b = *(const float4*)(wp + q * 8 + 4);
        wa0u = make_uint4(pack2(a.x, a.y), pack2(a.z, a.w), pack2(b.x, b.y), pack2(b.z, b.w));
        a = *(const float4*)(wp + 32 + q * 8); b = *(const float4*)(wp + 32 + q * 8 + 4);
        wa1u = make_uint4(pack2(a.x, a.y), pack2(a.z, a.w), pack2(b.x, b.y), pack2(b.z, b.w));
    }
    // B = h for node cl
    int node = blockIdx.x * 64 + wv * 16 + cl;
    node = node < NN ? node : NN - 1;   // clamped lanes duplicate NN-1 (same values)
    const u16* hp = h + (size_t)node * 64;
    bf16x8 bh0 = *(const bf16x8*)(hp + q * 8);
    bf16x8 bh1 = *(const bf16x8*)(hp + 32 + q * 8);
    __syncthreads();

    const f32x4 zero4 = {0.f, 0.f, 0.f, 0.f};
    f32x4 acc[8];
#pragma unroll
    for (int t = 0; t < 8; ++t) {
        bf16x8 a0 = *(const bf16x8*)(afrag + ((t * 2 + 0) * 64 + lane) * 8);
        bf16x8 a1 = *(const bf16x8*)(afrag + ((t * 2 + 1) * 64 + lane) * 8);
        acc[t] = MFMA16(a0, bh0, zero4);
        acc[t] = MFMA16(a1, bh1, acc[t]);
    }
    f32x4 aw = MFMA16(__builtin_bit_cast(bf16x8, wa0u), bh0, zero4);
    aw = MFMA16(__builtin_bit_cast(bf16x8, wa1u), bh1, aw);

    // stores: xh[node][c] = pack(head0 c, head1 c), c = t*16+q*4+r
#pragma unroll
    for (int t = 0; t < 4; ++t) {
        uint4 o;
        o.x = pack2c(acc[t][0], acc[t + 4][0]);
        o.y = pack2c(acc[t][1], acc[t + 4][1]);
        o.z = pack2c(acc[t][2], acc[t + 4][2]);
        o.w = pack2c(acc[t][3], acc[t + 4][3]);
        *((uint4*)(xh + (size_t)node * 64 + t * 16 + q * 4)) = o;
    }
    if (q == 0) {
        asrc[node] = make_float2(aw[0], aw[1]);
        adst[node] = make_float2(aw[2], aw[3]);
    }
}

// ------------------------- CSR build -------------------------
__global__ void hist_kernel(const int* __restrict__ ei, u32* __restrict__ deg) {
    int e = blockIdx.x * 256 + threadIdx.x;
    if (e < EE) atomicAdd(&deg[ei[EE + e]], 1u);
}

__global__ void scan1_kernel(u32* rp, u32* bsum) {
    __shared__ u32 tmp[256];
    int i = blockIdx.x * 256 + threadIdx.x;
    u32 v = (i < NN) ? rp[i] : 0u;
    tmp[threadIdx.x] = v;
    __syncthreads();
    for (int off = 1; off < 256; off <<= 1) {
        u32 t = (threadIdx.x >= (u32)off) ? tmp[threadIdx.x - off] : 0u;
        __syncthreads();
        tmp[threadIdx.x] += t;
        __syncthreads();
    }
    if (i < NN) rp[i] = tmp[threadIdx.x] - v;
    if (threadIdx.x == 255) bsum[blockIdx.x] = tmp[255];
}

__global__ void scan2_kernel(u32* bsum) {
    __shared__ u32 tmp[512];
    int tid = threadIdx.x;
    u32 v = (tid < 391) ? bsum[tid] : 0u;
    tmp[tid] = v;
    __syncthreads();
    for (int off = 1; off < 512; off <<= 1) {
        u32 t = (tid >= off) ? tmp[tid - off] : 0u;
        __syncthreads();
        tmp[tid] += t;
        __syncthreads();
    }
    if (tid < 391) bsum[tid] = tmp[tid] - v;
}

__global__ void scan3_kernel(u32* rp, const u32* __restrict__ bsum, u32* __restrict__ cursor) {
    int i = blockIdx.x * 256 + threadIdx.x;
    if (i < NN) {
        u32 v = rp[i] + bsum[blockIdx.x];
        rp[i] = v;
        cursor[i] = v;
    }
    if (blockIdx.x == 0 && threadIdx.x == 0) rp[NN] = EE;
}

__global__ void fill_kernel(const int* __restrict__ ei, u32* __restrict__ cursor,
                            int* __restrict__ csr) {
    int e = blockIdx.x * 256 + threadIdx.x;
    if (e < EE) {
        int s = ei[e], d = ei[EE + e];
        u32 p = atomicAdd(&cursor[d], 1u);
        csr[p] = s;
    }
}

// ---------------------------------------------------------------------------
// Gather: wave per node, lane = channel; z factors out; unroll-by-2 keeps two
// edges' dependent loads in flight. Fused bias+relu+linear+sigmoid epilogue.
// ---------------------------------------------------------------------------
__global__ __launch_bounds__(256) void gather_kernel(
    const u32* __restrict__ xh,
    const float2* __restrict__ asrc,
    const float2* __restrict__ adst,
    const u32* __restrict__ rp,
    const int* __restrict__ csr,
    const float* __restrict__ gat_b,  // [64]
    const float* __restrict__ lin_w,  // [2*64]
    const float* __restrict__ lin_b,  // [2]
    float2* __restrict__ out)         // [NN] (y0,y1) f32
{
    int wv = threadIdx.x >> 6, lane = threadIdx.x & 63;
    int node = blockIdx.x * 4 + wv;
    float2 ad = adst[node];
    float2 as = asrc[node];
    // self-loop
    float e0 = as.x + ad.x; e0 = e0 > 0.f ? e0 : 0.2f * e0;
    float e1 = as.y + ad.y; e1 = e1 > 0.f ? e1 : 0.2f * e1;
    float w0 = ex2(LOG2E * e0);
    float w1 = ex2(LOG2E * e1);
    u32 u = xh[(size_t)node * 64 + lane];
    float acc0 = w0 * bflo(u), acc1 = w1 * bfhi(u);
    float z0 = w0, z1 = w1;
    u32 beg = rp[node], end = rp[node + 1];
    u32 p = beg;
    for (; p + 2 <= end; p += 2) {
        int s0 = csr[p], s1 = csr[p + 1];
        float2 A0 = asrc[s0], A1 = asrc[s1];
        u32 u0 = xh[(size_t)s0 * 64 + lane];
        u32 u1 = xh[(size_t)s1 * 64 + lane];
        float f00 = A0.x + ad.x; f00 = f00 > 0.f ? f00 : 0.2f * f00;
        float f01 = A0.y + ad.y; f01 = f01 > 0.f ? f01 : 0.2f * f01;
        float f10 = A1.x + ad.x; f10 = f10 > 0.f ? f10 : 0.2f * f10;
        float f11 = A1.y + ad.y; f11 = f11 > 0.f ? f11 : 0.2f * f11;
        float v00 = ex2(LOG2E * f00);
        float v01 = ex2(LOG2E * f01);
        float v10 = ex2(LOG2E * f10);
        float v11 = ex2(LOG2E * f11);
        acc0 = fmaf(v00, bflo(u0), acc0);
        acc1 = fmaf(v01, bfhi(u0), acc1);
        acc0 = fmaf(v10, bflo(u1), acc0);
        acc1 = fmaf(v11, bfhi(u1), acc1);
        z0 += v00 + v10;
        z1 += v01 + v11;
    }
    if (p < end) {
        int s = csr[p];
        float2 a2 = asrc[s];
        u32 uu = xh[(size_t)s * 64 + lane];
        float f0 = a2.x + ad.x; f0 = f0 > 0.f ? f0 : 0.2f * f0;
        float f1 = a2.y + ad.y; f1 = f1 > 0.f ? f1 : 0.2f * f1;
        float v0 = ex2(LOG2E * f0);
        float v1 = ex2(LOG2E * f1);
        acc0 = fmaf(v0, bflo(uu), acc0);
        acc1 = fmaf(v1, bfhi(uu), acc1);
        z0 += v0;
        z1 += v1;
    }
    float od = 0.5f * (acc0 * fast_rcp(z0) + acc1 * fast_rcp(z1)) + gat_b[lane];
    od = fmaxf(od, 0.f);
    float p0 = od * lin_w[lane];
    float p1 = od * lin_w[64 + lane];
#pragma unroll
    for (int off = 32; off > 0; off >>= 1) {
        p0 += __shfl_xor(p0, off);
        p1 += __shfl_xor(p1, off);
    }
    if (lane == 0) {
        float y0 = fast_rcp(1.f + ex2(-LOG2E * (p0 + lin_b[0])));
        float y1 = fast_rcp(1.f + ex2(-LOG2E * (p1 + lin_b[1])));
        out[node] = make_float2(y0, y1);
    }
}

extern "C" void kernel_launch(void* const* d_in, const int* in_sizes, int n_in,
                              void* d_out, int out_size, void* d_ws, size_t ws_size,
                              hipStream_t stream) {
    const float* x = (const float*)d_in[0];
    const int* ei = (const int*)d_in[1];
    const float* w_ih = (const float*)d_in[2];
    const float* w_hh = (const float*)d_in[3];
    const float* b_ih = (const float*)d_in[4];
    const float* b_hh = (const float*)d_in[5];
    const float* gat_w = (const float*)d_in[6];
    const float* att_src = (const float*)d_in[7];
    const float* att_dst = (const float*)d_in[8];
    const float* gat_b = (const float*)d_in[9];
    const float* lin_w = (const float*)d_in[10];
    const float* lin_b = (const float*)d_in[11];

    char* w = (char*)d_ws;
    u16* h = (u16*)(w);                           // 12,800,000 B
    u32* xh = (u32*)(w + 12800000);               // 25,600,000 B
    float2* asrc = (float2*)(w + 38400000);       //    800,000 B
    float2* adst = (float2*)(w + 39200000);       //    800,000 B
    u32* rp = (u32*)(w + 40000000);               //    400,128 B (deg -> row_ptr)
    u32* cursor = (u32*)(w + 40400128);           //    400,000 B
    u32* bsum = (u32*)(w + 40800128);             //      2,048 B
    int* csr = (int*)(w + 40802176);              //  4,000,000 B
    float* watt = (float*)(w + 44802176);         //      1,024 B

    (void)hipMemsetAsync(rp, 0, (NN + 1) * sizeof(u32), stream);
    lstm_kernel<<<1563, 256, 0, stream>>>(x, w_ih, w_hh, b_ih, b_hh, h);
    watt_kernel<<<1, 256, 0, stream>>>(gat_w, att_src, att_dst, watt);
    xh_kernel<<<1563, 256, 0, stream>>>(h, gat_w, watt, xh, asrc, adst);
    hist_kernel<<<(EE + 255) / 256, 256, 0, stream>>>(ei, rp);
    scan1_kernel<<<391, 256, 0, stream>>>(rp, bsum);
    scan2_kernel<<<1, 512, 0, stream>>>(bsum);
    scan3_kernel<<<391, 256, 0, stream>>>(rp, bsum, cursor);
    fill_kernel<<<(EE + 255) / 256, 256, 0, stream>>>(ei, cursor, csr);
    gather_kernel<<<NN / 4, 256, 0, stream>>>(xh, asrc, adst, rp, csr, gat_b, lin_w, lin_b,
                                              (float2*)d_out);
}

// Round 2
// 783.778 us; speedup vs baseline: 1.0449x; 1.0448x over previous
//
#include <hip/hip_runtime.h>
#include <hip/hip_bf16.h>
#include <string.h>

#define NN 100000
#define TT 64
#define EE 1000000
#define LOG2E 1.44269504088896340736f

typedef __attribute__((ext_vector_type(8))) short bf16x8;
typedef __attribute__((ext_vector_type(4))) float f32x4;
typedef unsigned int u32;
typedef unsigned short u16;

__device__ __forceinline__ float bflo(u32 u) { return __builtin_bit_cast(float, u << 16); }
__device__ __forceinline__ float bfhi(u32 u) { return __builtin_bit_cast(float, u & 0xffff0000u); }
__device__ __forceinline__ u16 f2bf(float f) {
    u32 u = __builtin_bit_cast(u32, f);
    return (u16)((u + 0x7fffu + ((u >> 16) & 1u)) >> 16);
}
__device__ __forceinline__ u32 pack2(float a, float b) {
    return (u32)f2bf(a) | ((u32)f2bf(b) << 16);
}
// v_cvt_pk_bf16_f32 path (gfx950); memcpy avoids non-trivially-copyable bit_cast
__device__ __forceinline__ u32 pack2c(float a, float b) {
    __hip_bfloat162 t = __float22bfloat162_rn(make_float2(a, b));
    u32 r;
    __builtin_memcpy(&r, &t, 4);
    return r;
}
// raw v_exp_f32 — avoids OCML's guarded __ocml_exp2_f32 (harness compiles w/o -ffast-math)
__device__ __forceinline__ float ex2(float x) { return __builtin_amdgcn_exp2f(x); }
__device__ __forceinline__ float fast_rcp(float x) { return __builtin_amdgcn_rcpf(x); }
#define MFMA16(A, B, C) __builtin_amdgcn_mfma_f32_16x16x32_bf16((A), (B), (C), 0, 0, 0)

// ---------------------------------------------------------------------------
// LSTM gate-split (r13) + round-14: combined-reciprocal activations.
//   Wave w owns 64 gate rows (units 16w..16w+15 x {i,f,g,o}) for all 64 nodes
//   of the block; A (w_hh, pre-scaled by LOG2E / 2*LOG2E) in 32 VGPRs; tail
//   (w_ih,bias) in 4 hoisted bf16x8 frags; h block-shared, double-buffered
//   LDS [64][72]bf16 x2, one barrier per timestep.
//
//   Activation algebra (r14): per cell 5 exp + 2 rcp (was 5 exp + 5 rcp):
//     a=2^-accI b=2^-accG d=2^-accF e=2^-accO  (accG pre-scaled 2*LOG2E)
//     cc = (c*P + (1-b)*D1) * rcp(P*D1),  P=(1+a)(1+b), D1=(1+d)
//     h  = (1-t) * rcp((1+e)(1+t)),       t=2^(-2*LOG2E*cc)
//   Bounded: |c|<=T, products <= ~2^92 << f32 max; saturation degrades
//   gracefully (rcp(inf)=0 -> cc=0, matching the true limit).
//
// LAUNCH-BOUNDS LAWS (rounds 4-13):
//   * VGPR cap = 256/min_waves; min=3 (85 regs) spilled a big body once,
//     min=2 (128) never has.  Keep min=2; max raised 4->8 (r13 showed the
//     4-cap + flat perf at 2.6 blocks/CU resident).
//   * launch_bounds 2nd arg pins occupancy [a,a]; don't use it.
// ---------------------------------------------------------------------------
__global__ __launch_bounds__(256)
__attribute__((amdgpu_waves_per_eu(2, 8))) void lstm_kernel(
    const float* __restrict__ x,     // [NN*TT*2]
    const float* __restrict__ w_ih,  // [256*2]
    const float* __restrict__ w_hh,  // [256*64]
    const float* __restrict__ b_ih,  // [256]
    const float* __restrict__ b_hh,  // [256]
    u16* __restrict__ h_out)         // [NN*64] bf16 (internal format)
{
    __shared__ __align__(16) u16 h_sh[2][64 * 72];   // 18,432 B  double-buffered h
    __shared__ __align__(8) u32 x_lds[64 * 10];      //  2,560 B  packed bf16 x chunk

    const int tid = threadIdx.x;
    const int wv = tid >> 6, lane = tid & 63;
    const int q = lane >> 4, cl = lane & 15;

    // ---- stage A = w_hh fragments for this wave's 64 gate rows, in registers.
    bf16x8 aI0, aI1, aF0, aF1, aG0, aG1, aO0, aO1;
    bf16x8 wxI, wxF, wxG, wxO;   // tail frags: rows (wih0,wih1,bias,0..) q==0 only
    {
        const int rbase = wv * 16 + cl;
#define LOAD_A(D0, D1, G, SC)                                                \
        {                                                                    \
            const float* wr_ = w_hh + ((G) * 64 + rbase) * 64 + q * 8;       \
            float4 u0 = *(const float4*)(wr_);                               \
            float4 u1 = *(const float4*)(wr_ + 4);                           \
            uint4 t;                                                         \
            t.x = pack2(u0.x * (SC), u0.y * (SC));                           \
            t.y = pack2(u0.z * (SC), u0.w * (SC));                           \
            t.z = pack2(u1.x * (SC), u1.y * (SC));                           \
            t.w = pack2(u1.z * (SC), u1.w * (SC));                           \
            D0 = __builtin_bit_cast(bf16x8, t);                              \
            float4 v0 = *(const float4*)(wr_ + 32);                          \
            float4 v1 = *(const float4*)(wr_ + 36);                          \
            t.x = pack2(v0.x * (SC), v0.y * (SC));                           \
            t.y = pack2(v0.z * (SC), v0.w * (SC));                           \
            t.z = pack2(v1.x * (SC), v1.y * (SC));                           \
            t.w = pack2(v1.z * (SC), v1.w * (SC));                           \
            D1 = __builtin_bit_cast(bf16x8, t);                              \
        }
        LOAD_A(aI0, aI1, 0, LOG2E)
        LOAD_A(aF0, aF1, 1, LOG2E)
        LOAD_A(aG0, aG1, 2, 2.f * LOG2E)
        LOAD_A(aO0, aO1, 3, LOG2E)
#undef LOAD_A
#define LOAD_WT(D, G, SC)                                                    \
        {                                                                    \
            uint4 t = make_uint4(0u, 0u, 0u, 0u);                            \
            if (q == 0) {                                                    \
                int row = (G) * 64 + rbase;                                  \
                t.x = pack2(w_ih[row * 2 + 0] * (SC), w_ih[row * 2 + 1] * (SC)); \
                t.y = (u32)f2bf((b_ih[row] + b_hh[row]) * (SC));             \
            }                                                                \
            D = __builtin_bit_cast(bf16x8, t);                               \
        }
        LOAD_WT(wxI, 0, LOG2E)
        LOAD_WT(wxF, 1, LOG2E)
        LOAD_WT(wxG, 2, 2.f * LOG2E)
        LOAD_WT(wxO, 3, LOG2E)
#undef LOAD_WT
    }

    // zero h buffer 0 (step 0 reads it)
    {
        u32* z = (u32*)h_sh[0];
        for (int i = tid; i < 2304; i += 256) z[i] = 0u;
    }

    // x chunk plan: chunk = 8 steps; block-wide 256 float4 = 1/thread covers
    // 64 nodes x 8 steps x 2 comps.  thread -> (node = tid>>2, f4 = tid&3).
    const int nodeL = tid >> 2, f4 = tid & 3;
    int gnd = blockIdx.x * 64 + nodeL;
    gnd = gnd < NN ? gnd : NN - 1;
    const float* px = x + ((size_t)gnd * 64 + f4 * 2) * 2;
    float4 xr = *(const float4*)px;   // chunk 0 in flight

    float cst[16];
#pragma unroll
    for (int i = 0; i < 16; ++i) cst[i] = 0.f;

    const f32x4 zero4 = {0.f, 0.f, 0.f, 0.f};
    const int rd16 = cl * 72 + q * 8;            // B-frag u16 offset (+ct*1152)
    const int wr16 = cl * 72 + wv * 16 + q * 4;  // h-write u16 offset (+ct*1152)
    const int x16 = cl * 10;                     // x u32 offset (+ct*160)

    // one timestep: read h from HR, write new h to HW, x slot SL (0..7)
    auto step = [&](const u16* hr_, u16* hw_, int SL) {
#pragma unroll
        for (int ct = 0; ct < 4; ++ct) {
            bf16x8 bh0 = *(const bf16x8*)(hr_ + ct * 1152 + rd16);
            bf16x8 bh1 = *(const bf16x8*)(hr_ + ct * 1152 + rd16 + 32);
            uint4 xt;
            xt.x = x_lds[ct * 160 + x16 + SL];
            xt.y = 0x00003F80u;   // bf16(1.0) in slot k=2 (bias multiplier)
            xt.z = 0u; xt.w = 0u;
            bf16x8 bx = __builtin_bit_cast(bf16x8, xt);
            f32x4 accI, accF, accG, accO;
            accI = MFMA16(aI0, bh0, zero4);
            accI = MFMA16(aI1, bh1, accI);
            accI = MFMA16(wxI, bx, accI);
            accF = MFMA16(aF0, bh0, zero4);
            accF = MFMA16(aF1, bh1, accF);
            accF = MFMA16(wxF, bx, accF);
            accG = MFMA16(aG0, bh0, zero4);
            accG = MFMA16(aG1, bh1, accG);
            accG = MFMA16(wxG, bx, accG);
            accO = MFMA16(aO0, bh0, zero4);
            accO = MFMA16(aO1, bh1, accO);
            accO = MFMA16(wxO, bx, accO);
            // elementwise: node = 16ct+cl, unit u = 16*wv + 4q + r
            // combined-reciprocal form: 5 exp + 2 rcp per cell
            float h0, h1, h2, h3;
#define ACT(R, HOUT)                                                       \
            {                                                              \
                float a_ = ex2(-accI[R]);                                  \
                float b_ = ex2(-accG[R]);                                  \
                float d_ = ex2(-accF[R]);                                  \
                float e_ = ex2(-accO[R]);                                  \
                float P = (1.f + a_) * (1.f + b_);                         \
                float D1 = 1.f + d_;                                       \
                float num = fmaf(cst[ct * 4 + R], P, (1.f - b_) * D1);     \
                float cc = num * fast_rcp(P * D1);                         \
                cst[ct * 4 + R] = cc;                                      \
                float t_ = ex2(-2.f * LOG2E * cc);                         \
                float R2 = (1.f + e_) * (1.f + t_);                        \
                HOUT = (1.f - t_) * fast_rcp(R2);                          \
            }
            ACT(0, h0) ACT(1, h1) ACT(2, h2) ACT(3, h3)
#undef ACT
            *((uint2*)(hw_ + ct * 1152 + wr16)) =
                make_uint2(pack2c(h0, h1), pack2c(h2, h3));
        }
    };

    for (int c = 0; c < 8; ++c) {
        // commit chunk c (prev steps all barriered -> WAR on x_lds safe)
        *((uint2*)(x_lds + nodeL * 10 + f4 * 2)) =
            make_uint2(pack2c(xr.x, xr.y), pack2c(xr.z, xr.w));
        if (c < 7) xr = *(const float4*)(px + (c + 1) * 16);
        __syncthreads();  // x_lds (and chunk-0: zeroed h) visible
        for (int s2 = 0; s2 < 4; ++s2) {
            step(h_sh[0], h_sh[1], s2 * 2);
            __syncthreads();
            step(h_sh[1], h_sh[0], s2 * 2 + 1);
            __syncthreads();
        }
    }
    // 64 steps done, final h in h_sh[0]; write coalesced u32 pairs
#pragma unroll
    for (int i = 0; i < 8; ++i) {
        int id = i * 256 + tid;
        int row = id >> 5, col2 = (id & 31) * 2;
        int nd = blockIdx.x * 64 + row;
        if (nd < NN) {
            u32 u = *(const u32*)(h_sh[0] + row * 72 + col2);
            *((u32*)(h_out + (size_t)nd * 64 + col2)) = u;
        }
    }
}

// ---------------------------------------------------------------------------
// watt[v][k] = sum_d att_v[d] * gat_w[head_v*64+d][k]   (v: 0=src h0, 1=src h1,
// 2=dst h0, 3=dst h1).  Folds attention dots into the xh GEMM as extra rows.
// ---------------------------------------------------------------------------
__global__ void watt_kernel(const float* __restrict__ gat_w,
                            const float* __restrict__ att_src,
                            const float* __restrict__ att_dst,
                            float* __restrict__ watt) {  // [4*64]
    int tid = threadIdx.x;
    int v = tid >> 6, k = tid & 63;
    int head = v & 1;
    const float* att = (v < 2) ? att_src : att_dst;
    float acc = 0.f;
#pragma unroll 8
    for (int d = 0; d < 64; ++d)
        acc = fmaf(att[head * 64 + d], gat_w[(head * 64 + d) * 64 + k], acc);
    watt[v * 64 + k] = acc;
}

// ---------------------------------------------------------------------------
// xh via MFMA: one wave per 16 nodes. A = gat_w tiles (LDS), B = h (global).
// D[col = t*16+q*4+r][node = cl]; tiles t/t+4 = head0/head1 at same lane.
// watt tile: q==0 lanes hold (asrc0, asrc1, adst0, adst1) for node cl.
// ---------------------------------------------------------------------------
__global__ __launch_bounds__(256, 2) void xh_kernel(
    const u16* __restrict__ h,        // [NN*64] bf16 (internal)
    const float* __restrict__ gat_w,  // [128*64] f32
    const float* __restrict__ watt,   // [4*64] f32
    u32* __restrict__ xh,             // [NN*64] packed bf16 pairs
    float2* __restrict__ asrc,
    float2* __restrict__ adst)
{
    __shared__ __align__(16) u16 afrag[16 * 64 * 8];   // 16 KB
    const int tid = threadIdx.x;
    const int wv = tid >> 6, lane = tid & 63;
    const int q = lane >> 4, cl = lane & 15;

    // stage A = gat_w fragments (tile t: rows t*16..+15 = output cols)
    for (int f = wv; f < 16; f += 4) {
        int t = f >> 1, kh = f & 1;
        const float4* s4 = (const float4*)(gat_w + (t * 16 + cl) * 64 + kh * 32 + q * 8);
        float4 u0 = s4[0], u1 = s4[1];
        u16* d = afrag + (f * 64 + lane) * 8;
        d[0] = f2bf(u0.x); d[1] = f2bf(u0.y); d[2] = f2bf(u0.z); d[3] = f2bf(u0.w);
        d[4] = f2bf(u1.x); d[5] = f2bf(u1.y); d[6] = f2bf(u1.z); d[7] = f2bf(u1.w);
    }
    // watt A-fragments in registers (rows cl<4 = att vectors, else 0)
    uint4 wa0u = make_uint4(0u, 0u, 0u, 0u), wa1u = wa0u;
    if (cl < 4) {
        const float* wp = watt + cl * 64;
        float4 a = *(const float4*)(wp + q * 8), b = *(const float4*)(wp + q * 8 + 4);
        wa0u = make_uint4(pack2(a.x, a.y), pack2(a.z, a.w), pack2(b.x, b.y), pack2(b.z, b.w));
        a = *(const float4*)(wp + 32 + q * 8); b = *(const float4*)(wp + 32 + q * 8 + 4);
        wa1u = make_uint4(pack2(a.x, a.y), pack2(a.z, a.w), pack2(b.x, b.y), pack2(b.z, b.w));
    }
    // B = h for node cl
    int node = blockIdx.x * 64 + wv * 16 + cl;
    node = node < NN ? node : NN - 1;   // clamped lanes duplicate NN-1 (same values)
    const u16* hp = h + (size_t)node * 64;
    bf16x8 bh0 = *(const bf16x8*)(hp + q * 8);
    bf16x8 bh1 = *(const bf16x8*)(hp + 32 + q * 8);
    __syncthreads();

    const f32x4 zero4 = {0.f, 0.f, 0.f, 0.f};
    f32x4 acc[8];
#pragma unroll
    for (int t = 0; t < 8; ++t) {
        bf16x8 a0 = *(const bf16x8*)(afrag + ((t * 2 + 0) * 64 + lane) * 8);
        bf16x8 a1 = *(const bf16x8*)(afrag + ((t * 2 + 1) * 64 + lane) * 8);
        acc[t] = MFMA16(a0, bh0, zero4);
        acc[t] = MFMA16(a1, bh1, acc[t]);
    }
    f32x4 aw = MFMA16(__builtin_bit_cast(bf16x8, wa0u), bh0, zero4);
    aw = MFMA16(__builtin_bit_cast(bf16x8, wa1u), bh1, aw);

    // stores: xh[node][c] = pack(head0 c, head1 c), c = t*16+q*4+r
#pragma unroll
    for (int t = 0; t < 4; ++t) {
        uint4 o;
        o.x = pack2c(acc[t][0], acc[t + 4][0]);
        o.y = pack2c(acc[t][1], acc[t + 4][1]);
        o.z = pack2c(acc[t][2], acc[t + 4][2]);
        o.w = pack2c(acc[t][3], acc[t + 4][3]);
        *((uint4*)(xh + (size_t)node * 64 + t * 16 + q * 4)) = o;
    }
    if (q == 0) {
        asrc[node] = make_float2(aw[0], aw[1]);
        adst[node] = make_float2(aw[2], aw[3]);
    }
}

// ------------------------- CSR build -------------------------
__global__ void hist_kernel(const int* __restrict__ ei, u32* __restrict__ deg) {
    int e = blockIdx.x * 256 + threadIdx.x;
    if (e < EE) atomicAdd(&deg[ei[EE + e]], 1u);
}

__global__ void scan1_kernel(u32* rp, u32* bsum) {
    __shared__ u32 tmp[256];
    int i = blockIdx.x * 256 + threadIdx.x;
    u32 v = (i < NN) ? rp[i] : 0u;
    tmp[threadIdx.x] = v;
    __syncthreads();
    for (int off = 1; off < 256; off <<= 1) {
        u32 t = (threadIdx.x >= (u32)off) ? tmp[threadIdx.x - off] : 0u;
        __syncthreads();
        tmp[threadIdx.x] += t;
        __syncthreads();
    }
    if (i < NN) rp[i] = tmp[threadIdx.x] - v;
    if (threadIdx.x == 255) bsum[blockIdx.x] = tmp[255];
}

__global__ void scan2_kernel(u32* bsum) {
    __shared__ u32 tmp[512];
    int tid = threadIdx.x;
    u32 v = (tid < 391) ? bsum[tid] : 0u;
    tmp[tid] = v;
    __syncthreads();
    for (int off = 1; off < 512; off <<= 1) {
        u32 t = (tid >= off) ? tmp[tid - off] : 0u;
        __syncthreads();
        tmp[tid] += t;
        __syncthreads();
    }
    if (tid < 391) bsum[tid] = tmp[tid] - v;
}

__global__ void scan3_kernel(u32* rp, const u32* __restrict__ bsum, u32* __restrict__ cursor) {
    int i = blockIdx.x * 256 + threadIdx.x;
    if (i < NN) {
        u32 v = rp[i] + bsum[blockIdx.x];
        rp[i] = v;
        cursor[i] = v;
    }
    if (blockIdx.x == 0 && threadIdx.x == 0) rp[NN] = EE;
}

__global__ void fill_kernel(const int* __restrict__ ei, u32* __restrict__ cursor,
                            int* __restrict__ csr) {
    int e = blockIdx.x * 256 + threadIdx.x;
    if (e < EE) {
        int s = ei[e], d = ei[EE + e];
        u32 p = atomicAdd(&cursor[d], 1u);
        csr[p] = s;
    }
}

// ---------------------------------------------------------------------------
// Gather: wave per node, lane = channel; z factors out; unroll-by-2 keeps two
// edges' dependent loads in flight. Fused bias+relu+linear+sigmoid epilogue.
// ---------------------------------------------------------------------------
__global__ __launch_bounds__(256) void gather_kernel(
    const u32* __restrict__ xh,
    const float2* __restrict__ asrc,
    const float2* __restrict__ adst,
    const u32* __restrict__ rp,
    const int* __restrict__ csr,
    const float* __restrict__ gat_b,  // [64]
    const float* __restrict__ lin_w,  // [2*64]
    const float* __restrict__ lin_b,  // [2]
    float2* __restrict__ out)         // [NN] (y0,y1) f32
{
    int wv = threadIdx.x >> 6, lane = threadIdx.x & 63;
    int node = blockIdx.x * 4 + wv;
    float2 ad = adst[node];
    float2 as = asrc[node];
    // self-loop
    float e0 = as.x + ad.x; e0 = e0 > 0.f ? e0 : 0.2f * e0;
    float e1 = as.y + ad.y; e1 = e1 > 0.f ? e1 : 0.2f * e1;
    float w0 = ex2(LOG2E * e0);
    float w1 = ex2(LOG2E * e1);
    u32 u = xh[(size_t)node * 64 + lane];
    float acc0 = w0 * bflo(u), acc1 = w1 * bfhi(u);
    float z0 = w0, z1 = w1;
    u32 beg = rp[node], end = rp[node + 1];
    u32 p = beg;
    for (; p + 2 <= end; p += 2) {
        int s0 = csr[p], s1 = csr[p + 1];
        float2 A0 = asrc[s0], A1 = asrc[s1];
        u32 u0 = xh[(size_t)s0 * 64 + lane];
        u32 u1 = xh[(size_t)s1 * 64 + lane];
        float f00 = A0.x + ad.x; f00 = f00 > 0.f ? f00 : 0.2f * f00;
        float f01 = A0.y + ad.y; f01 = f01 > 0.f ? f01 : 0.2f * f01;
        float f10 = A1.x + ad.x; f10 = f10 > 0.f ? f10 : 0.2f * f10;
        float f11 = A1.y + ad.y; f11 = f11 > 0.f ? f11 : 0.2f * f11;
        float v00 = ex2(LOG2E * f00);
        float v01 = ex2(LOG2E * f01);
        float v10 = ex2(LOG2E * f10);
        float v11 = ex2(LOG2E * f11);
        acc0 = fmaf(v00, bflo(u0), acc0);
        acc1 = fmaf(v01, bfhi(u0), acc1);
        acc0 = fmaf(v10, bflo(u1), acc0);
        acc1 = fmaf(v11, bfhi(u1), acc1);
        z0 += v00 + v10;
        z1 += v01 + v11;
    }
    if (p < end) {
        int s = csr[p];
        float2 a2 = asrc[s];
        u32 uu = xh[(size_t)s * 64 + lane];
        float f0 = a2.x + ad.x; f0 = f0 > 0.f ? f0 : 0.2f * f0;
        float f1 = a2.y + ad.y; f1 = f1 > 0.f ? f1 : 0.2f * f1;
        float v0 = ex2(LOG2E * f0);
        float v1 = ex2(LOG2E * f1);
        acc0 = fmaf(v0, bflo(uu), acc0);
        acc1 = fmaf(v1, bfhi(uu), acc1);
        z0 += v0;
        z1 += v1;
    }
    float od = 0.5f * (acc0 * fast_rcp(z0) + acc1 * fast_rcp(z1)) + gat_b[lane];
    od = fmaxf(od, 0.f);
    float p0 = od * lin_w[lane];
    float p1 = od * lin_w[64 + lane];
#pragma unroll
    for (int off = 32; off > 0; off >>= 1) {
        p0 += __shfl_xor(p0, off);
        p1 += __shfl_xor(p1, off);
    }
    if (lane == 0) {
        float y0 = fast_rcp(1.f + ex2(-LOG2E * (p0 + lin_b[0])));
        float y1 = fast_rcp(1.f + ex2(-LOG2E * (p1 + lin_b[1])));
        out[node] = make_float2(y0, y1);
    }
}

extern "C" void kernel_launch(void* const* d_in, const int* in_sizes, int n_in,
                              void* d_out, int out_size, void* d_ws, size_t ws_size,
                              hipStream_t stream) {
    const float* x = (const float*)d_in[0];
    const int* ei = (const int*)d_in[1];
    const float* w_ih = (const float*)d_in[2];
    const float* w_hh = (const float*)d_in[3];
    const float* b_ih = (const float*)d_in[4];
    const float* b_hh = (const float*)d_in[5];
    const float* gat_w = (const float*)d_in[6];
    const float* att_src = (const float*)d_in[7];
    const float* att_dst = (const float*)d_in[8];
    const float* gat_b = (const float*)d_in[9];
    const float* lin_w = (const float*)d_in[10];
    const float* lin_b = (const float*)d_in[11];

    char* w = (char*)d_ws;
    u16* h = (u16*)(w);                           // 12,800,000 B
    u32* xh = (u32*)(w + 12800000);               // 25,600,000 B
    float2* asrc = (float2*)(w + 38400000);       //    800,000 B
    float2* adst = (float2*)(w + 39200000);       //    800,000 B
    u32* rp = (u32*)(w + 40000000);               //    400,128 B (deg -> row_ptr)
    u32* cursor = (u32*)(w + 40400128);           //    400,000 B
    u32* bsum = (u32*)(w + 40800128);             //      2,048 B
    int* csr = (int*)(w + 40802176);              //  4,000,000 B
    float* watt = (float*)(w + 44802176);         //      1,024 B

    (void)hipMemsetAsync(rp, 0, (NN + 1) * sizeof(u32), stream);
    lstm_kernel<<<1563, 256, 0, stream>>>(x, w_ih, w_hh, b_ih, b_hh, h);
    watt_kernel<<<1, 256, 0, stream>>>(gat_w, att_src, att_dst, watt);
    xh_kernel<<<1563, 256, 0, stream>>>(h, gat_w, watt, xh, asrc, adst);
    hist_kernel<<<(EE + 255) / 256, 256, 0, stream>>>(ei, rp);
    scan1_kernel<<<391, 256, 0, stream>>>(rp, bsum);
    scan2_kernel<<<1, 512, 0, stream>>>(bsum);
    scan3_kernel<<<391, 256, 0, stream>>>(rp, bsum, cursor);
    fill_kernel<<<(EE + 255) / 256, 256, 0, stream>>>(ei, cursor, csr);
    gather_kernel<<<NN / 4, 256, 0, stream>>>(xh, asrc, adst, rp, csr, gat_b, lin_w, lin_b,
                                              (float2*)d_out);
}